// Round 4
// baseline (567.957 us; speedup 1.0000x reference)
//
#include <hip/hip_runtime.h>
#include <hip/hip_cooperative_groups.h>
#include <math.h>

namespace cg = cooperative_groups;

#define NLEV 5
#define TOPKK 1000
#define NCLS 16
#define NPART 16
#define PART_CAP 256
#define CAND_TOT 2048
#define NTOT 785664u
#define HISTSZ (NLEV * 256)
#define NBLK 512
#define NTHR 256

// level boundaries; sizes: 589824, 147456, 36864, 9216, 2304
__device__ __forceinline__ int find_level(unsigned i, unsigned& loc) {
    if (i < 589824u) { loc = i;            return 0; }
    if (i < 737280u) { loc = i - 589824u;  return 1; }
    if (i < 774144u) { loc = i - 737280u;  return 2; }
    if (i < 783360u) { loc = i - 774144u;  return 3; }
    loc = i - 783360u; return 4;
}

// order-preserving float32 -> uint32 (larger uint == larger float)
__device__ __forceinline__ unsigned f2key(float f) {
    unsigned u = __float_as_uint(f);
    return (u & 0x80000000u) ? ~u : (u | 0x80000000u);
}

__device__ __forceinline__ float max4(float4 v) {
    return fmaxf(fmaxf(v.x, v.y), fmaxf(v.z, v.w));
}

struct Args {
    const float* anc[NLEV];
    const float* cls[NLEV];
    const float* reg[NLEV];
    unsigned* keys;            // 785664 u32
    unsigned* histA;           // NPART*HISTSZ u32
    unsigned* histB;           // NPART*HISTSZ u32 (aliases cand region)
    unsigned long long* cand;  // 5*NPART*PART_CAP u64
    unsigned* prefix;          // 5 u32
    unsigned* remaining;       // 5 u32
    unsigned* cnt;             // 5*NPART u32
    float4* wsbox;             // 5000 boxes, rank-ordered
    unsigned* sidx;            // 5000 winner indices, rank-ordered
    float* out;
};

// per-level 256-bin suffix-select: find bin holding the k-th largest
__device__ void select_bin(const unsigned* hist, unsigned* s, unsigned* prefix,
                           unsigned* remaining, int shift, int first) {
    int l = blockIdx.x;                 // blocks 0..4 == level
    int t = threadIdx.x, r = 255 - t;   // scan over r == suffix over bin
    unsigned c = 0;
    #pragma unroll
    for (int pp = 0; pp < NPART; pp++) c += hist[pp * HISTSZ + l * 256 + t];
    s[r] = c;
    __syncthreads();
    for (int d = 1; d < 256; d <<= 1) {
        unsigned v = (r >= d) ? s[r - d] : 0u;
        __syncthreads();
        s[r] += v;
        __syncthreads();
    }
    unsigned incl = s[r], above = incl - c;
    unsigned rem = first ? (unsigned)TOPKK : remaining[l];
    unsigned pf = first ? 0u : prefix[l];
    if (above < rem && rem <= incl) {
        prefix[l] = pf | (((unsigned)t) << shift);
        remaining[l] = rem - above;
    }
}

__global__ __launch_bounds__(NTHR, 2) void k_all(Args a) {
    cg::grid_group grid = cg::this_grid();
    __shared__ __align__(16) unsigned char smraw[16384 + 256];
    unsigned* lh = (unsigned*)smraw;                       // hist / scan
    unsigned long long* lbuf = (unsigned long long*)smraw; // candidate stage
    unsigned* aux = (unsigned*)(smraw + 16384);            // small per-phase
    const unsigned gid = blockIdx.x * NTHR + threadIdx.x;
    const unsigned GT = NBLK * NTHR;

    // ---- P0: zero counters (ws is 0xAA-poisoned each call) ----
    for (unsigned i = gid; i < (unsigned)(NPART * HISTSZ); i += GT) {
        a.histA[i] = 0u;
        a.histB[i] = 0u;
    }
    if (gid < NLEV * NPART) a.cnt[gid] = 0u;
    grid.sync();

    // ---- P1: keys = sortable(max16 logits); 8-bit MSB hist ----
    for (int t = threadIdx.x; t < HISTSZ; t += NTHR) lh[t] = 0u;
    __syncthreads();
    for (unsigned i = gid; i < NTOT; i += GT) {
        unsigned loc; int l = find_level(i, loc);
        const float4* c = (const float4*)(a.cls[l]) + (size_t)loc * 4;
        float4 v0 = c[0], v1 = c[1], v2 = c[2], v3 = c[3];
        float m = max4(v0);
        m = fmaxf(m, max4(v1));
        m = fmaxf(m, max4(v2));
        m = fmaxf(m, max4(v3));
        unsigned k = f2key(m);
        a.keys[i] = k;
        atomicAdd(&lh[l * 256 + (k >> 24)], 1u);
    }
    __syncthreads();
    {
        unsigned part = blockIdx.x & (NPART - 1);
        for (int t = threadIdx.x; t < HISTSZ; t += NTHR)
            if (lh[t]) atomicAdd(&a.histA[part * HISTSZ + t], lh[t]);
    }
    grid.sync();

    // ---- P2: select top byte (blocks 0..4, one level each) ----
    if (blockIdx.x < NLEV)
        select_bin(a.histA, lh, a.prefix, a.remaining, 24, 1);
    grid.sync();

    // ---- P3: second-byte hist of keys matching top byte ----
    for (int t = threadIdx.x; t < HISTSZ; t += NTHR) lh[t] = 0u;
    if (threadIdx.x < NLEV) aux[threadIdx.x] = a.prefix[threadIdx.x];
    __syncthreads();
    for (unsigned i = gid; i < NTOT; i += GT) {
        unsigned loc; int l = find_level(i, loc);
        unsigned k = a.keys[i];
        if ((k & 0xFF000000u) == aux[l])
            atomicAdd(&lh[l * 256 + ((k >> 16) & 0xFFu)], 1u);
    }
    __syncthreads();
    {
        unsigned part = blockIdx.x & (NPART - 1);
        for (int t = threadIdx.x; t < HISTSZ; t += NTHR)
            if (lh[t]) atomicAdd(&a.histB[part * HISTSZ + t], lh[t]);
    }
    grid.sync();

    // ---- P4: select second byte ----
    if (blockIdx.x < NLEV)
        select_bin(a.histB, lh, a.prefix, a.remaining, 16, 0);
    grid.sync();

    // ---- P5: compact keys >= 16-bit floor into NPART segments/level ----
    if (threadIdx.x < NLEV) aux[threadIdx.x] = a.prefix[threadIdx.x];
    __syncthreads();
    for (unsigned i = gid; i < NTOT; i += GT) {
        unsigned loc; int l = find_level(i, loc);
        unsigned k = a.keys[i];
        if (k >= aux[l]) {          // prefix low 16 bits are zero
            unsigned part = blockIdx.x & (NPART - 1);
            unsigned slot = atomicAdd(&a.cnt[l * NPART + part], 1u);
            if (slot < PART_CAP)
                a.cand[((size_t)(l * NPART + part)) * PART_CAP + slot] =
                    ((unsigned long long)k << 32) | (unsigned)(~loc);
        }
    }
    grid.sync();

    // ---- P6: rank-by-counting; winners decode box, scatter by rank ----
    // blocks 8l..8l+7 handle level l; unique ranks (index bits differ);
    // composite desc == key desc then index asc == lax.top_k tie rule
    if (blockIdx.x < NLEV * 8) {
        int l = blockIdx.x >> 3;
        unsigned sl = blockIdx.x & 7;
        if (threadIdx.x < NPART) {
            unsigned cc = a.cnt[l * NPART + threadIdx.x];
            aux[threadIdx.x] = (cc > PART_CAP) ? PART_CAP : cc;
        }
        __syncthreads();
        if (threadIdx.x == 0) {
            unsigned o = 0;
            for (int pp = 0; pp < NPART; pp++) { aux[16 + pp] = o; o += aux[pp]; }
            aux[32] = (o > CAND_TOT) ? CAND_TOT : o;
        }
        __syncthreads();
        unsigned n = aux[32];
        for (int pp = 0; pp < NPART; pp++) {
            unsigned cc = aux[pp], o = aux[16 + pp];
            for (unsigned e = threadIdx.x; e < cc; e += NTHR) {
                unsigned dst = o + e;
                if (dst < CAND_TOT)
                    lbuf[dst] = a.cand[((size_t)(l * NPART + pp)) * PART_CAP + e];
            }
        }
        __syncthreads();
        unsigned j = sl * NTHR + threadIdx.x;
        if (j < n) {
            unsigned long long my = lbuf[j];
            unsigned rank = 0;
            #pragma unroll 4
            for (unsigned q = 0; q < n; q++) rank += (lbuf[q] > my) ? 1u : 0u;
            if (rank < TOPKK) {
                const float MAXD = 4.135166556742356f;   // log(1000/16)
                unsigned idx = ~((unsigned)(my & 0xFFFFFFFFull));
                float4 an = ((const float4*)a.anc[l])[idx];
                float4 dd = ((const float4*)a.reg[l])[(size_t)idx * 2];
                float w = an.z - an.x, h = an.w - an.y;
                float cx = an.x + 0.5f * w, cy = an.y + 0.5f * h;
                float pcx = cx + dd.x * w, pcy = cy + dd.y * h;
                float pw = w * expf(fminf(dd.z, MAXD));
                float ph = h * expf(fminf(dd.w, MAXD));
                a.wsbox[l * TOPKK + rank] = make_float4(
                    pcx - 0.5f * pw, pcy - 0.5f * ph,
                    pcx + 0.5f * pw, pcy + 0.5f * ph);
                a.sidx[l * TOPKK + rank] = idx;
            }
        }
    }
    grid.sync();

    // ---- P7: emit 80000 rows ----
    for (unsigned r = gid; r < (unsigned)(NLEV * TOPKK * NCLS); r += GT) {
        unsigned j = r >> 4, c = r & 15u;
        unsigned l = j / TOPKK;
        unsigned idx = a.sidx[j];
        float4 b = a.wsbox[j];
        float sc = a.cls[l][(size_t)idx * NCLS + c];
        sc = 1.0f / (1.0f + expf(-sc));
        float* q = a.out + (size_t)r * 6;
        q[0] = b.x; q[1] = b.y; q[2] = b.z; q[3] = b.w;
        q[4] = sc;  q[5] = (float)(c + 1);
    }
}

extern "C" void kernel_launch(void* const* d_in, const int* in_sizes, int n_in,
                              void* d_out, int out_size, void* d_ws, size_t ws_size,
                              hipStream_t stream) {
    Args a;
    for (int l = 0; l < NLEV; l++) {
        a.anc[l] = (const float*)d_in[3 * l + 0];
        a.cls[l] = (const float*)d_in[3 * l + 1];
        a.reg[l] = (const float*)d_in[3 * l + 2];
    }
    char* w = (char*)d_ws;
    // layout (bytes):
    //   keys   : 0        .. 3142656   (785664 u32)
    //   histA  : 3142656  .. +81920
    //   cand   : 3224576  .. +163840   (histB aliases first 81920 B; cand
    //                                   written only after histB is dead)
    //   prefix : 3388416  .. +32
    //   remain : 3388448  .. +32
    //   cnt    : 3388480  .. +320
    //   wsbox  : 3388800  .. +80000    (16B aligned)
    //   sidx   : 3468800  .. +20000
    a.keys      = (unsigned*)w;
    a.histA     = (unsigned*)(w + 3142656);
    a.cand      = (unsigned long long*)(w + 3224576);
    a.histB     = (unsigned*)(w + 3224576);
    a.prefix    = (unsigned*)(w + 3388416);
    a.remaining = (unsigned*)(w + 3388448);
    a.cnt       = (unsigned*)(w + 3388480);
    a.wsbox     = (float4*)(w + 3388800);
    a.sidx      = (unsigned*)(w + 3468800);
    a.out       = (float*)d_out;

    void* kp[] = { &a };
    (void)hipLaunchCooperativeKernel((const void*)k_all, dim3(NBLK), dim3(NTHR),
                                     kp, 0, stream);
}

// Round 5
// 195.914 us; speedup vs baseline: 2.8990x; 2.8990x over previous
//
#include <hip/hip_runtime.h>
#include <math.h>

#define NLEV 5
#define TOPKK 1000
#define NCLS 16
#define NPART 16
#define PART_CAP 256
#define CAND_TOT 2048
#define NTOT 785664u
#define HISTSZ (NLEV * 256)

// level boundaries; sizes: 589824, 147456, 36864, 9216, 2304
__device__ __forceinline__ int find_level(unsigned i, unsigned& loc) {
    if (i < 589824u) { loc = i;            return 0; }
    if (i < 737280u) { loc = i - 589824u;  return 1; }
    if (i < 774144u) { loc = i - 737280u;  return 2; }
    if (i < 783360u) { loc = i - 774144u;  return 3; }
    loc = i - 783360u; return 4;
}

struct Ptrs {
    const float* anc[NLEV];
    const float* cls[NLEV];
    const float* reg[NLEV];
};

// order-preserving float32 -> uint32 (larger uint == larger float)
__device__ __forceinline__ unsigned f2key(float f) {
    unsigned u = __float_as_uint(f);
    return (u & 0x80000000u) ? ~u : (u | 0x80000000u);
}

__device__ __forceinline__ float max4(float4 v) {
    return fmaxf(fmaxf(v.x, v.y), fmaxf(v.z, v.w));
}

// keys = sortable(max over 16 logits); 8-bit MSB hist into NPART partials
__global__ void k_keys_hist(Ptrs p, unsigned* keys, unsigned* hist) {
    __shared__ unsigned lh[HISTSZ];
    for (int t = threadIdx.x; t < HISTSZ; t += blockDim.x) lh[t] = 0u;
    __syncthreads();
    unsigned i = blockIdx.x * blockDim.x + threadIdx.x;
    if (i < NTOT) {
        unsigned loc; int l = find_level(i, loc);
        const float4* c = (const float4*)(p.cls[l]) + (size_t)loc * 4;
        float4 a = c[0], b = c[1], d = c[2], e = c[3];
        float m = max4(a);
        m = fmaxf(m, max4(b));
        m = fmaxf(m, max4(d));
        m = fmaxf(m, max4(e));
        unsigned k = f2key(m);
        keys[i] = k;
        atomicAdd(&lh[l * 256 + (k >> 24)], 1u);
    }
    __syncthreads();
    unsigned part = blockIdx.x & (NPART - 1);
    for (int t = threadIdx.x; t < HISTSZ; t += blockDim.x)
        if (lh[t]) atomicAdd(&hist[part * HISTSZ + t], lh[t]);
}

// second radix pass: bits [16:23] of keys whose top byte matches prefix
__global__ void k_hist2(const unsigned* keys, const unsigned* prefix, unsigned* hist) {
    __shared__ unsigned lh[HISTSZ];
    __shared__ unsigned pf[NLEV];
    for (int t = threadIdx.x; t < HISTSZ; t += blockDim.x) lh[t] = 0u;
    if (threadIdx.x < NLEV) pf[threadIdx.x] = prefix[threadIdx.x];
    __syncthreads();
    unsigned i = blockIdx.x * blockDim.x + threadIdx.x;
    if (i < NTOT) {
        unsigned loc; int l = find_level(i, loc);
        unsigned k = keys[i];
        if ((k & 0xFF000000u) == pf[l])
            atomicAdd(&lh[l * 256 + ((k >> 16) & 0xFFu)], 1u);
    }
    __syncthreads();
    unsigned part = blockIdx.x & (NPART - 1);
    for (int t = threadIdx.x; t < HISTSZ; t += blockDim.x)
        if (lh[t]) atomicAdd(&hist[part * HISTSZ + t], lh[t]);
}

// grid = 5 blocks, one level each: reduce NPART partials, find the radix bin
// holding the k-th largest; also zero `zbuf` for the next pipeline stage
__global__ void k_select(unsigned* hist, unsigned* prefix, unsigned* remaining,
                         int shift, int first, unsigned* zbuf, unsigned zn) {
    __shared__ unsigned s[256];
    int l = blockIdx.x;
    int t = threadIdx.x, r = 255 - t;   // scan over r == suffix over bin
    unsigned c = 0;
    #pragma unroll
    for (int pp = 0; pp < NPART; pp++) c += hist[pp * HISTSZ + l * 256 + t];
    s[r] = c;
    __syncthreads();
    for (int d = 1; d < 256; d <<= 1) {
        unsigned v = (r >= d) ? s[r - d] : 0u;
        __syncthreads();
        s[r] += v;
        __syncthreads();
    }
    unsigned incl = s[r], above = incl - c;
    unsigned rem = first ? (unsigned)TOPKK : remaining[l];
    unsigned pf = first ? 0u : prefix[l];
    if (above < rem && rem <= incl) {   // exactly one winner thread per level
        prefix[l] = pf | (((unsigned)t) << shift);
        remaining[l] = rem - above;
    }
    // zero duty for next stage (histB before hist2 / cnt before compact)
    for (unsigned i = blockIdx.x * 256u + t; i < zn; i += NLEV * 256u)
        zbuf[i] = 0u;
}

// keep every key >= 16-bit bucket floor into NPART segments per level
__global__ void k_compact(const unsigned* keys, const unsigned* prefix,
                          unsigned* cnt, unsigned long long* cand) {
    unsigned i = blockIdx.x * blockDim.x + threadIdx.x;
    if (i >= NTOT) return;
    unsigned loc; int l = find_level(i, loc);
    unsigned k = keys[i];
    if (k >= prefix[l]) {            // prefix low 16 bits are zero
        unsigned part = blockIdx.x & (NPART - 1);
        unsigned slot = atomicAdd(&cnt[l * NPART + part], 1u);
        if (slot < PART_CAP)
            cand[((size_t)(l * NPART + part)) * PART_CAP + slot] =
                ((unsigned long long)k << 32) | (unsigned)(~loc);
    }
}

// 8 blocks/level: stage candidates in LDS, rank-by-counting (composite desc
// == key desc, index asc == lax.top_k tie rule; ranks unique since index
// bits differ), winners decode box + write their 16 output rows directly
__global__ __launch_bounds__(256) void k_rank_emit(Ptrs p, const unsigned* cnt,
                                                   const unsigned long long* cand,
                                                   float* out) {
    const float MAXD = 4.135166556742356f;   // log(1000/16)
    int l = blockIdx.x >> 3;
    unsigned sl = blockIdx.x & 7;
    int t = threadIdx.x;
    __shared__ unsigned long long lbuf[CAND_TOT];
    __shared__ unsigned aux[33];

    if (t < NPART) {
        unsigned cc = cnt[l * NPART + t];
        aux[t] = (cc > PART_CAP) ? PART_CAP : cc;
    }
    __syncthreads();
    if (t == 0) {
        unsigned o = 0;
        for (int pp = 0; pp < NPART; pp++) { aux[16 + pp] = o; o += aux[pp]; }
        aux[32] = (o > CAND_TOT) ? CAND_TOT : o;
    }
    __syncthreads();
    unsigned n = aux[32];
    for (int pp = 0; pp < NPART; pp++) {
        unsigned cc = aux[pp], o = aux[16 + pp];
        for (unsigned e = t; e < cc; e += 256) {
            unsigned dst = o + e;
            if (dst < CAND_TOT)
                lbuf[dst] = cand[((size_t)(l * NPART + pp)) * PART_CAP + e];
        }
    }
    __syncthreads();

    unsigned j = sl * 256u + t;
    if (j >= n) return;
    unsigned long long my = lbuf[j];
    unsigned rank = 0;
    #pragma unroll 8
    for (unsigned q = 0; q < n; q++) rank += (lbuf[q] > my) ? 1u : 0u;
    if (rank >= TOPKK) return;

    unsigned idx = ~((unsigned)(my & 0xFFFFFFFFull));
    float4 an = ((const float4*)p.anc[l])[idx];
    float4 dd = ((const float4*)p.reg[l])[(size_t)idx * 2];
    float w = an.z - an.x, h = an.w - an.y;
    float cx = an.x + 0.5f * w, cy = an.y + 0.5f * h;
    float pcx = cx + dd.x * w, pcy = cy + dd.y * h;
    float pw = w * expf(fminf(dd.z, MAXD));
    float ph = h * expf(fminf(dd.w, MAXD));
    float bx = pcx - 0.5f * pw, by = pcy - 0.5f * ph;
    float bz = pcx + 0.5f * pw, bw = pcy + 0.5f * ph;

    const float4* cp = (const float4*)(p.cls[l]) + (size_t)idx * 4;
    float sg[16];
    #pragma unroll
    for (int g = 0; g < 4; g++) {
        float4 v = cp[g];
        sg[4 * g + 0] = 1.0f / (1.0f + expf(-v.x));
        sg[4 * g + 1] = 1.0f / (1.0f + expf(-v.y));
        sg[4 * g + 2] = 1.0f / (1.0f + expf(-v.z));
        sg[4 * g + 3] = 1.0f / (1.0f + expf(-v.w));
    }
    // 16 rows of [bx,by,bz,bw,score,tag] == 24 float4s, 384B contiguous
    float4* q = (float4*)(out + (size_t)(l * TOPKK + rank) * (NCLS * 6));
    #pragma unroll
    for (int g = 0; g < 8; g++) {
        float ta = (float)(2 * g + 1), tb = (float)(2 * g + 2);
        q[3 * g + 0] = make_float4(bx, by, bz, bw);
        q[3 * g + 1] = make_float4(sg[2 * g], ta, bx, by);
        q[3 * g + 2] = make_float4(bz, bw, sg[2 * g + 1], tb);
    }
}

extern "C" void kernel_launch(void* const* d_in, const int* in_sizes, int n_in,
                              void* d_out, int out_size, void* d_ws, size_t ws_size,
                              hipStream_t stream) {
    Ptrs p;
    for (int l = 0; l < NLEV; l++) {
        p.anc[l] = (const float*)d_in[3 * l + 0];
        p.cls[l] = (const float*)d_in[3 * l + 1];
        p.reg[l] = (const float*)d_in[3 * l + 2];
    }
    char* w = (char*)d_ws;
    // layout (bytes):
    //   keys   : 0        .. 3142656   (785664 u32)
    //   histA  : 3142656  .. +81920    (zeroed by memset)
    //   histB  : 3224576  .. +81920    (zeroed by select1)
    //   cand   : 3306496  .. +163840
    //   prefix : 3470336  .. +32       (assigned, no pre-zero)
    //   remain : 3470368  .. +32       (assigned, no pre-zero)
    //   cnt    : 3470400  .. +320      (zeroed by select2)
    unsigned* keys      = (unsigned*)w;
    unsigned* histA     = (unsigned*)(w + 3142656);
    unsigned* histB     = (unsigned*)(w + 3224576);
    unsigned long long* cand = (unsigned long long*)(w + 3306496);
    unsigned* prefix    = (unsigned*)(w + 3470336);
    unsigned* remaining = (unsigned*)(w + 3470368);
    unsigned* cnt       = (unsigned*)(w + 3470400);

    float* out = (float*)d_out;
    int nb = (NTOT + 255) / 256;

    (void)hipMemsetAsync(histA, 0, 81920, stream);
    k_keys_hist<<<nb, 256, 0, stream>>>(p, keys, histA);
    k_select<<<NLEV, 256, 0, stream>>>(histA, prefix, remaining, 24, 1,
                                       histB, HISTSZ * NPART);
    k_hist2<<<nb, 256, 0, stream>>>(keys, prefix, histB);
    k_select<<<NLEV, 256, 0, stream>>>(histB, prefix, remaining, 16, 0,
                                       cnt, NLEV * NPART);
    k_compact<<<nb, 256, 0, stream>>>(keys, prefix, cnt, cand);
    k_rank_emit<<<NLEV * 8, 256, 0, stream>>>(p, cnt, cand, out);
}

// Round 6
// 187.501 us; speedup vs baseline: 3.0291x; 1.0449x over previous
//
#include <hip/hip_runtime.h>
#include <math.h>

#define NLEV 5
#define TOPKK 1000
#define NCLS 16
#define NPART 16
#define PART_CAP 256
#define CAND_TOT 2048
#define NTOT 785664u
#define HISTSZ (NLEV * 256)

// level boundaries; sizes: 589824, 147456, 36864, 9216, 2304
// ALL boundaries are multiples of 256 -> a 256-thread block never straddles
__device__ __forceinline__ int find_level(unsigned i, unsigned& loc) {
    if (i < 589824u) { loc = i;            return 0; }
    if (i < 737280u) { loc = i - 589824u;  return 1; }
    if (i < 774144u) { loc = i - 737280u;  return 2; }
    if (i < 783360u) { loc = i - 774144u;  return 3; }
    loc = i - 783360u; return 4;
}

struct Ptrs {
    const float* anc[NLEV];
    const float* cls[NLEV];
    const float* reg[NLEV];
};

// order-preserving float32 -> uint32 (larger uint == larger float)
__device__ __forceinline__ unsigned f2key(float f) {
    unsigned u = __float_as_uint(f);
    return (u & 0x80000000u) ? ~u : (u | 0x80000000u);
}

__device__ __forceinline__ float max4(float4 v) {
    return fmaxf(fmaxf(v.x, v.y), fmaxf(v.z, v.w));
}

// per-block redundant radix select for level l: reduce NPART partials over
// 256 bins, suffix-scan, find bin holding the rem_in-th largest.
// aux[0] <- pf_acc | bin<<shift ; aux[1] <- rem within that bin.
// blockDim must be 256.
__device__ void level_select(const unsigned* histbase, int l, int shift,
                             unsigned rem_in, unsigned pf_acc,
                             unsigned* s, unsigned* aux) {
    int t = threadIdx.x, r = 255 - t;     // scan over r == suffix over bin
    unsigned c = 0;
    #pragma unroll
    for (int pp = 0; pp < NPART; pp++) c += histbase[pp * HISTSZ + l * 256 + t];
    s[r] = c;
    __syncthreads();
    for (int d = 1; d < 256; d <<= 1) {
        unsigned v = (r >= d) ? s[r - d] : 0u;
        __syncthreads();
        s[r] += v;
        __syncthreads();
    }
    unsigned incl = s[r], above = incl - c;
    if (above < rem_in && rem_in <= incl) {      // exactly one winner thread
        aux[0] = pf_acc | (((unsigned)t) << shift);
        aux[1] = rem_in - above;
    }
    __syncthreads();
}

// keys = sortable(max over 16 logits); 8-bit MSB hist (own level's 256 bins)
__global__ __launch_bounds__(256) void k_keys_hist(Ptrs p, unsigned* keys,
                                                   unsigned* hist) {
    __shared__ unsigned lh[256];
    lh[threadIdx.x] = 0u;
    __syncthreads();
    unsigned i = blockIdx.x * 256u + threadIdx.x;      // NTOT == 3069*256
    unsigned loc; int l = find_level(i, loc);
    const float4* c = (const float4*)(p.cls[l]) + (size_t)loc * 4;
    float4 a = c[0], b = c[1], d = c[2], e = c[3];
    float m = max4(a);
    m = fmaxf(m, max4(b));
    m = fmaxf(m, max4(d));
    m = fmaxf(m, max4(e));
    unsigned k = f2key(m);
    keys[i] = k;
    atomicAdd(&lh[k >> 24], 1u);
    __syncthreads();
    unsigned part = blockIdx.x & (NPART - 1);
    if (lh[threadIdx.x])
        atomicAdd(&hist[part * HISTSZ + l * 256 + threadIdx.x], lh[threadIdx.x]);
}

// inline select-1 from histA, then hist byte [16:23] of matching keys
__global__ __launch_bounds__(256) void k_hist2(const unsigned* keys,
                                               const unsigned* histA,
                                               unsigned* histB) {
    __shared__ unsigned s[256];
    __shared__ unsigned lh[256];
    __shared__ unsigned aux[2];
    unsigned i0 = blockIdx.x * 256u;
    unsigned loc0; int l = find_level(i0, loc0);
    level_select(histA, l, 24, TOPKK, 0u, s, aux);
    unsigned pf = aux[0];
    lh[threadIdx.x] = 0u;
    __syncthreads();
    unsigned k = keys[i0 + threadIdx.x];
    if ((k & 0xFF000000u) == pf)
        atomicAdd(&lh[(k >> 16) & 0xFFu], 1u);
    __syncthreads();
    unsigned part = blockIdx.x & (NPART - 1);
    if (lh[threadIdx.x])
        atomicAdd(&histB[part * HISTSZ + l * 256 + threadIdx.x], lh[threadIdx.x]);
}

// inline select-1 + select-2, then compact keys >= 16-bit floor
__global__ __launch_bounds__(256) void k_compact(const unsigned* keys,
                                                 const unsigned* histA,
                                                 const unsigned* histB,
                                                 unsigned* cnt,
                                                 unsigned long long* cand) {
    __shared__ unsigned s[256];
    __shared__ unsigned aux[2];
    unsigned i0 = blockIdx.x * 256u;
    unsigned loc0; int l = find_level(i0, loc0);
    level_select(histA, l, 24, TOPKK, 0u, s, aux);
    unsigned pf1 = aux[0], rem1 = aux[1];
    __syncthreads();
    level_select(histB, l, 16, rem1, pf1, s, aux);
    unsigned thresh = aux[0];                 // low 16 bits are zero
    unsigned k = keys[i0 + threadIdx.x];
    if (k >= thresh) {
        unsigned loc = loc0 + threadIdx.x;
        unsigned part = blockIdx.x & (NPART - 1);
        unsigned slot = atomicAdd(&cnt[l * NPART + part], 1u);
        if (slot < PART_CAP)
            cand[((size_t)(l * NPART + part)) * PART_CAP + slot] =
                ((unsigned long long)k << 32) | (unsigned)(~loc);
    }
}

// 8 blocks/level: stage candidates in LDS, rank-by-counting (composite desc
// == key desc, index asc == lax.top_k tie rule; ranks unique since index
// bits differ), winners decode box + write their 16 output rows directly
__global__ __launch_bounds__(256) void k_rank_emit(Ptrs p, const unsigned* cnt,
                                                   const unsigned long long* cand,
                                                   float* out) {
    const float MAXD = 4.135166556742356f;   // log(1000/16)
    int l = blockIdx.x >> 3;
    unsigned sl = blockIdx.x & 7;
    int t = threadIdx.x;
    __shared__ unsigned long long lbuf[CAND_TOT];
    __shared__ unsigned aux[33];

    if (t < NPART) {
        unsigned cc = cnt[l * NPART + t];
        aux[t] = (cc > PART_CAP) ? PART_CAP : cc;
    }
    __syncthreads();
    if (t == 0) {
        unsigned o = 0;
        for (int pp = 0; pp < NPART; pp++) { aux[16 + pp] = o; o += aux[pp]; }
        aux[32] = (o > CAND_TOT) ? CAND_TOT : o;
    }
    __syncthreads();
    unsigned n = aux[32];
    for (int pp = 0; pp < NPART; pp++) {
        unsigned cc = aux[pp], o = aux[16 + pp];
        for (unsigned e = t; e < cc; e += 256) {
            unsigned dst = o + e;
            if (dst < CAND_TOT)
                lbuf[dst] = cand[((size_t)(l * NPART + pp)) * PART_CAP + e];
        }
    }
    __syncthreads();

    unsigned j = sl * 256u + t;
    if (j >= n) return;
    unsigned long long my = lbuf[j];
    unsigned rank = 0;
    #pragma unroll 8
    for (unsigned q = 0; q < n; q++) rank += (lbuf[q] > my) ? 1u : 0u;
    if (rank >= TOPKK) return;

    unsigned idx = ~((unsigned)(my & 0xFFFFFFFFull));
    float4 an = ((const float4*)p.anc[l])[idx];
    float4 dd = ((const float4*)p.reg[l])[(size_t)idx * 2];
    float w = an.z - an.x, h = an.w - an.y;
    float cx = an.x + 0.5f * w, cy = an.y + 0.5f * h;
    float pcx = cx + dd.x * w, pcy = cy + dd.y * h;
    float pw = w * expf(fminf(dd.z, MAXD));
    float ph = h * expf(fminf(dd.w, MAXD));
    float bx = pcx - 0.5f * pw, by = pcy - 0.5f * ph;
    float bz = pcx + 0.5f * pw, bw = pcy + 0.5f * ph;

    const float4* cp = (const float4*)(p.cls[l]) + (size_t)idx * 4;
    float sg[16];
    #pragma unroll
    for (int g = 0; g < 4; g++) {
        float4 v = cp[g];
        sg[4 * g + 0] = 1.0f / (1.0f + expf(-v.x));
        sg[4 * g + 1] = 1.0f / (1.0f + expf(-v.y));
        sg[4 * g + 2] = 1.0f / (1.0f + expf(-v.z));
        sg[4 * g + 3] = 1.0f / (1.0f + expf(-v.w));
    }
    // 16 rows of [bx,by,bz,bw,score,tag] == 24 float4s, 384B contiguous
    float4* q = (float4*)(out + (size_t)(l * TOPKK + rank) * (NCLS * 6));
    #pragma unroll
    for (int g = 0; g < 8; g++) {
        float ta = (float)(2 * g + 1), tb = (float)(2 * g + 2);
        q[3 * g + 0] = make_float4(bx, by, bz, bw);
        q[3 * g + 1] = make_float4(sg[2 * g], ta, bx, by);
        q[3 * g + 2] = make_float4(bz, bw, sg[2 * g + 1], tb);
    }
}

extern "C" void kernel_launch(void* const* d_in, const int* in_sizes, int n_in,
                              void* d_out, int out_size, void* d_ws, size_t ws_size,
                              hipStream_t stream) {
    Ptrs p;
    for (int l = 0; l < NLEV; l++) {
        p.anc[l] = (const float*)d_in[3 * l + 0];
        p.cls[l] = (const float*)d_in[3 * l + 1];
        p.reg[l] = (const float*)d_in[3 * l + 2];
    }
    char* w = (char*)d_ws;
    // layout (bytes):
    //   keys   : 0        .. 3142656   (785664 u32)
    //   histA  : 3142656  .. +81920    \
    //   histB  : 3224576  .. +81920     } one contiguous memset (164160 B)
    //   cnt    : 3306496  .. +320      /
    //   cand   : 3306816  .. +163840
    unsigned* keys  = (unsigned*)w;
    unsigned* histA = (unsigned*)(w + 3142656);
    unsigned* histB = (unsigned*)(w + 3224576);
    unsigned* cnt   = (unsigned*)(w + 3306496);
    unsigned long long* cand = (unsigned long long*)(w + 3306816);

    float* out = (float*)d_out;
    int nb = NTOT / 256;                     // 3069, exact

    (void)hipMemsetAsync(histA, 0, 164160, stream);
    k_keys_hist<<<nb, 256, 0, stream>>>(p, keys, histA);
    k_hist2<<<nb, 256, 0, stream>>>(keys, histA, histB);
    k_compact<<<nb, 256, 0, stream>>>(keys, histA, histB, cnt, cand);
    k_rank_emit<<<NLEV * 8, 256, 0, stream>>>(p, cnt, cand, out);
}